// Round 8
// baseline (896.881 us; speedup 1.0000x reference)
//
#include <hip/hip_runtime.h>
#include <hip/hip_bf16.h>
#include <math.h>

#define N_NODES 50000
#define N_EDGES 800000
#define ATT_SCALE 0.125f    // 1/sqrt(64)

typedef __attribute__((ext_vector_type(8))) short bf16x8;
typedef __attribute__((ext_vector_type(4))) float f32x4;

__device__ __forceinline__ unsigned short f2bf(float f) {
  __hip_bfloat16 h = __float2bfloat16(f);
  unsigned short u; __builtin_memcpy(&u, &h, 2); return u;
}
__device__ __forceinline__ float bf2f(unsigned short u) {
  __hip_bfloat16 h; __builtin_memcpy(&h, &u, 2); return __bfloat162float(h);
}
__device__ __forceinline__ void gload16(const void* g, void* l) {
  __builtin_amdgcn_global_load_lds(
      (const __attribute__((address_space(1))) unsigned int*)g,
      (__attribute__((address_space(3))) unsigned int*)l, 16, 0, 0);
}

// ---------------------------------------------------------------- CSR build
__global__ void zero_int(int* __restrict__ p, int n) {
  int i = blockIdx.x * blockDim.x + threadIdx.x;
  if (i < n) p[i] = 0;
}

__global__ void hist_kernel(const int* __restrict__ dst, int* __restrict__ counts, int e) {
  int i = blockIdx.x * blockDim.x + threadIdx.x;
  if (i < e) atomicAdd(&counts[dst[i]], 1);
}

// parallel scan, stage 1: per-block (1024) local exclusive scan + block total
__global__ __launch_bounds__(1024) void scan1_kernel(const int* __restrict__ counts,
                                                     int* __restrict__ offsets,
                                                     int* __restrict__ btot, int n) {
  __shared__ int wsum[16];
  const int tid = threadIdx.x;
  const int lane = tid & 63, wid = tid >> 6;
  int idx = blockIdx.x * 1024 + tid;
  int v = (idx < n) ? counts[idx] : 0;
  int s = v;
#pragma unroll
  for (int off = 1; off < 64; off <<= 1) {
    int t = __shfl_up(s, off);
    if (lane >= off) s += t;
  }
  if (lane == 63) wsum[wid] = s;
  __syncthreads();
  if (wid == 0) {
    int wsv = (lane < 16) ? wsum[lane] : 0;
#pragma unroll
    for (int off = 1; off < 16; off <<= 1) {
      int t = __shfl_up(wsv, off);
      if (lane >= off) wsv += t;
    }
    if (lane < 16) wsum[lane] = wsv;
  }
  __syncthreads();
  int wbase = (wid > 0) ? wsum[wid - 1] : 0;
  if (idx < n) offsets[idx] = wbase + s - v;   // block-local exclusive
  if (tid == 0) btot[blockIdx.x] = wsum[15];
}

// stage 2: one wave exclusive-scans the <=64 block totals in place
__global__ __launch_bounds__(64) void scan2_kernel(int* __restrict__ btot, int nb) {
  int lane = threadIdx.x;
  int v = (lane < nb) ? btot[lane] : 0;
  int s = v;
#pragma unroll
  for (int off = 1; off < 64; off <<= 1) {
    int t = __shfl_up(s, off);
    if (lane >= off) s += t;
  }
  if (lane < nb) btot[lane] = s - v;
}

// stage 3: add block bases; write both offsets and cursor
__global__ void scan3_kernel(int* __restrict__ offsets, int* __restrict__ cursor,
                             const int* __restrict__ btot, int n) {
  int i = blockIdx.x * blockDim.x + threadIdx.x;
  if (i < n) {
    int o = offsets[i] + btot[i >> 10];
    offsets[i] = o;
    cursor[i] = o;
  }
}

// legacy single-block scan (fallback path only)
__global__ __launch_bounds__(1024) void scan_kernel(const int* __restrict__ counts,
                                                    int* __restrict__ offsets,
                                                    int* __restrict__ cursor, int n) {
  __shared__ int wsum[16];
  const int tid = threadIdx.x;
  const int lane = tid & 63, wid = tid >> 6;
  int carry = 0;
  for (int base = 0; base < n; base += 1024) {
    int idx = base + tid;
    int v = (idx < n) ? counts[idx] : 0;
    int s = v;
#pragma unroll
    for (int off = 1; off < 64; off <<= 1) {
      int t = __shfl_up(s, off);
      if (lane >= off) s += t;
    }
    if (lane == 63) wsum[wid] = s;
    __syncthreads();
    if (wid == 0) {
      int wsv = (lane < 16) ? wsum[lane] : 0;
#pragma unroll
      for (int off = 1; off < 16; off <<= 1) {
        int t = __shfl_up(wsv, off);
        if (lane >= off) wsv += t;
      }
      if (lane < 16) wsum[lane] = wsv;
    }
    __syncthreads();
    int wbase = (wid > 0) ? wsum[wid - 1] : 0;
    if (idx < n) {
      int ex = carry + wbase + s - v;
      offsets[idx] = ex;
      cursor[idx] = ex;
    }
    int total = wsum[15];
    __syncthreads();
    carry += total;
  }
  if (tid == 0) offsets[n] = carry;
}

__global__ void fill_kernel(const int* __restrict__ src, const int* __restrict__ dst,
                            int* __restrict__ cursor, int* __restrict__ ssrc, int e) {
  int i = blockIdx.x * blockDim.x + threadIdx.x;
  if (i < e) {
    int d = dst[i];
    int slot = atomicAdd(&cursor[d], 1);
    ssrc[slot] = src[i];
  }
}

// per-node insertion sort of the adjacency segment (ascending src id).
// creates temporal locality: all waves sweep src-space in the same direction.
__global__ void sort_kernel(const int* __restrict__ offsets, const int* __restrict__ counts,
                            int* __restrict__ ssrc) {
  int i = blockIdx.x * blockDim.x + threadIdx.x;
  if (i >= N_NODES) return;
  int beg = offsets[i], cnt = counts[i];
  for (int a = 1; a < cnt; a++) {
    int key = ssrc[beg + a];
    int b = a - 1;
    while (b >= 0 && ssrc[beg + b] > key) {
      ssrc[beg + b + 1] = ssrc[beg + b];
      b--;
    }
    ssrc[beg + b + 1] = key;
  }
}

// ---------------------------------------------------------------- converts
__global__ void convert_x_kernel(const float* __restrict__ x,
                                 unsigned short* __restrict__ Ahi,
                                 unsigned short* __restrict__ Alo) {
  int t = blockIdx.x * blockDim.x + threadIdx.x;   // N*64
  int row = t >> 6, g = (t & 63) * 4;
  if (row >= N_NODES) return;
  float4 xv = *(const float4*)(x + (size_t)row * 256 + g);
  ushort4 hi, lo;
  hi.x = f2bf(xv.x); lo.x = f2bf(xv.x - bf2f(hi.x));
  hi.y = f2bf(xv.y); lo.y = f2bf(xv.y - bf2f(hi.y));
  hi.z = f2bf(xv.z); lo.z = f2bf(xv.z - bf2f(hi.z));
  hi.w = f2bf(xv.w); lo.w = f2bf(xv.w - bf2f(hi.w));
  *(ushort4*)(Ahi + (size_t)row * 256 + g) = hi;
  *(ushort4*)(Alo + (size_t)row * 256 + g) = lo;
}

// Bexp[l][n][0:256]=hi(W[k][n]), [256:512]=lo, [512:768]=hi   (k-contiguous rows)
__global__ void convert_w_kernel(const float* __restrict__ Wq, const float* __restrict__ Wk,
                                 const float* __restrict__ Wv, const float* __restrict__ Ws,
                                 unsigned short* __restrict__ Bexp) {
  int t = blockIdx.x * blockDim.x + threadIdx.x;   // 3*256*1024
  if (t >= 3 * 256 * 1024) return;
  int n = t & 1023;
  int k = (t >> 10) & 255;
  int l = t >> 18;
  const float* W = (n < 256) ? Wq : (n < 512) ? Wk : (n < 768) ? Wv : Ws;
  float w = W[l * 65536 + k * 256 + (n & 255)];
  unsigned short hi = f2bf(w);
  unsigned short lo = f2bf(w - bf2f(hi));
  unsigned short* row = Bexp + ((size_t)l * 1024 + n) * 768;
  row[k] = hi; row[256 + k] = lo; row[512 + k] = hi;
}

// ---------------------------------------------------------------- bf16 MFMA GEMM
// logical out[N,1024] = [Q|K|V|S]; Q -> bf16 [N,256]; K,V interleaved KV [N,512]
// bf16 (K in cols 0:256, V in 256:512); S -> fp32 [N,256].
// Phase A: stage Ahi once with BOTH B slices -> 64 MFMA per barrier-pair.
// Phase B: Alo x W_hi. tile 128x128, 4 waves 2x2, mfma 16x16x32; XCD swizzle.
__global__ __launch_bounds__(256) void bgemm_kernel(
    const unsigned short* __restrict__ Ahi,   // [N(+pad)][256]
    const unsigned short* __restrict__ Alo,   // [N(+pad)][256]
    const unsigned short* __restrict__ B,     // [3][1024][768]
    const float* __restrict__ bq, const float* __restrict__ bk,
    const float* __restrict__ bv, const float* __restrict__ bs,
    int layer,
    unsigned short* __restrict__ Qb,          // [N][256] bf16
    unsigned short* __restrict__ KVb,         // [N][512] bf16 (K|V)
    float* __restrict__ Sf) {                 // [N][256] fp32
  __shared__ __align__(16) char lds[49152];
  char* Al  = lds;
  char* Bl1 = lds + 16384;
  char* Bl2 = lds + 32768;

  // XCD-aware swizzle (bijective: 3128 = 8*391)
  const int orig = blockIdx.x;
  const int swz = (orig & 7) * 391 + (orig >> 3);
  const int nb = swz & 7;                  // col block of 128 (fastest in-chunk)
  const int m0 = (swz >> 3) * 128;

  const int tid = threadIdx.x;
  const int wid = tid >> 6;
  const int lane = tid & 63;
  const int l15 = lane & 15, lhi = lane >> 4;
  const int wr = wid >> 1, wc = wid & 1;   // wave grid 2x2

  const char* Ag_hi = (const char*)Ahi;
  const char* Ag_lo = (const char*)Alo;
  const char* Bg = (const char*)(B + ((size_t)layer * 1024 + nb * 128) * 768);

  f32x4 acc[4][4];
#pragma unroll
  for (int m = 0; m < 4; m++)
#pragma unroll
    for (int n = 0; n < 4; n++) acc[m][n] = (f32x4){0.f, 0.f, 0.f, 0.f};

  const int swzl = (l15 & 7) << 4;

  // ---- phase A: Ahi x (W_hi | W_lo) -------------------------------------
  for (int kt4 = 0; kt4 < 4; kt4++) {
    const int ka2 = kt4 * 128;           // byte offset of 64-k chunk in 512B row
#pragma unroll
    for (int i = 0; i < 4; i++) {
      int o = tid * 16 + i * 4096;
      int row = o >> 7;
      int sg = ((o >> 4) & 7) ^ (row & 7);
      gload16(Ag_hi + (size_t)(m0 + row) * 512 + ka2 + sg * 16, Al  + wid * 1024 + i * 4096);
      gload16(Bg + (size_t)row * 1536 + ka2 + sg * 16,          Bl1 + wid * 1024 + i * 4096);
      gload16(Bg + (size_t)row * 1536 + 512 + ka2 + sg * 16,    Bl2 + wid * 1024 + i * 4096);
    }
    __syncthreads();

    bf16x8 af[2][4], bfrag[2][4];
#pragma unroll
    for (int kk = 0; kk < 2; kk++)
#pragma unroll
      for (int m = 0; m < 4; m++) {
        af[kk][m]    = *(const bf16x8*)(Al  + (wr * 64 + m * 16 + l15) * 128 + ((kk * 64 + lhi * 16) ^ swzl));
        bfrag[kk][m] = *(const bf16x8*)(Bl1 + (wc * 64 + m * 16 + l15) * 128 + ((kk * 64 + lhi * 16) ^ swzl));
      }
#pragma unroll
    for (int kk = 0; kk < 2; kk++)
#pragma unroll
      for (int m = 0; m < 4; m++)
#pragma unroll
        for (int n = 0; n < 4; n++)
          acc[m][n] = __builtin_amdgcn_mfma_f32_16x16x32_bf16(af[kk][m], bfrag[kk][n], acc[m][n], 0, 0, 0);
#pragma unroll
    for (int kk = 0; kk < 2; kk++)
#pragma unroll
      for (int m = 0; m < 4; m++)
        bfrag[kk][m] = *(const bf16x8*)(Bl2 + (wc * 64 + m * 16 + l15) * 128 + ((kk * 64 + lhi * 16) ^ swzl));
#pragma unroll
    for (int kk = 0; kk < 2; kk++)
#pragma unroll
      for (int m = 0; m < 4; m++)
#pragma unroll
        for (int n = 0; n < 4; n++)
          acc[m][n] = __builtin_amdgcn_mfma_f32_16x16x32_bf16(af[kk][m], bfrag[kk][n], acc[m][n], 0, 0, 0);
    __syncthreads();
  }

  // ---- phase B: Alo x W_hi (rows 512+k) ---------------------------------
  for (int kt4 = 0; kt4 < 4; kt4++) {
    const int ka2 = kt4 * 128;
#pragma unroll
    for (int i = 0; i < 4; i++) {
      int o = tid * 16 + i * 4096;
      int row = o >> 7;
      int sg = ((o >> 4) & 7) ^ (row & 7);
      gload16(Ag_lo + (size_t)(m0 + row) * 512 + ka2 + sg * 16, Al  + wid * 1024 + i * 4096);
      gload16(Bg + (size_t)row * 1536 + 1024 + ka2 + sg * 16,   Bl1 + wid * 1024 + i * 4096);
    }
    __syncthreads();

    bf16x8 af[2][4], bfrag[2][4];
#pragma unroll
    for (int kk = 0; kk < 2; kk++)
#pragma unroll
      for (int m = 0; m < 4; m++) {
        af[kk][m]    = *(const bf16x8*)(Al  + (wr * 64 + m * 16 + l15) * 128 + ((kk * 64 + lhi * 16) ^ swzl));
        bfrag[kk][m] = *(const bf16x8*)(Bl1 + (wc * 64 + m * 16 + l15) * 128 + ((kk * 64 + lhi * 16) ^ swzl));
      }
#pragma unroll
    for (int kk = 0; kk < 2; kk++)
#pragma unroll
      for (int m = 0; m < 4; m++)
#pragma unroll
        for (int n = 0; n < 4; n++)
          acc[m][n] = __builtin_amdgcn_mfma_f32_16x16x32_bf16(af[kk][m], bfrag[kk][n], acc[m][n], 0, 0, 0);
    __syncthreads();
  }

  // ---- epilogue ---------------------------------------------------------
  const float* bias = ((nb < 2) ? bq : (nb < 4) ? bk : (nb < 6) ? bv : bs) + layer * 256 + (nb & 1) * 128;
  float bn[4];
#pragma unroll
  for (int n = 0; n < 4; n++) bn[n] = bias[wc * 64 + n * 16 + l15];

  const int col = (nb & 1) * 128 + wc * 64 + l15;
  if (nb < 2) {
#pragma unroll
    for (int m = 0; m < 4; m++) {
#pragma unroll
      for (int r = 0; r < 4; r++) {
        int row = m0 + wr * 64 + m * 16 + lhi * 4 + r;
        if (row < N_NODES) {
          unsigned short* orow = Qb + (size_t)row * 256 + col;
#pragma unroll
          for (int n = 0; n < 4; n++) orow[n * 16] = f2bf(acc[m][n][r] + bn[n]);
        }
      }
    }
  } else if (nb < 6) {
    const int col512 = ((nb >= 4) ? 256 : 0) + col;   // K in [0,256), V in [256,512)
#pragma unroll
    for (int m = 0; m < 4; m++) {
#pragma unroll
      for (int r = 0; r < 4; r++) {
        int row = m0 + wr * 64 + m * 16 + lhi * 4 + r;
        if (row < N_NODES) {
          unsigned short* orow = KVb + (size_t)row * 512 + col512;
#pragma unroll
          for (int n = 0; n < 4; n++) orow[n * 16] = f2bf(acc[m][n][r] + bn[n]);
        }
      }
    }
  } else {
#pragma unroll
    for (int m = 0; m < 4; m++) {
#pragma unroll
      for (int r = 0; r < 4; r++) {
        int row = m0 + wr * 64 + m * 16 + lhi * 4 + r;
        if (row < N_NODES) {
          float* orow = Sf + (size_t)row * 256 + col;
#pragma unroll
          for (int n = 0; n < 4; n++) orow[n * 16] = acc[m][n][r] + bn[n];
        }
      }
    }
  }
}

// ---------------------------------------------------------------- attention
// one wave per dst node; lane l: head l>>4, channels (l&15)*4..+3.
// Q bf16 [N,256]; KV bf16 [N,512] (K|V interleaved); S fp32 [N,256].
// 4-chain unrolled online softmax; adjacency sorted by src -> temporal locality.
// MODE 0: write fp32 [N,256] to hout. MODE 1: write split-bf16 Ahi/Alo.
template <int MODE>
__global__ __launch_bounds__(256) void attn_kernel(
    const unsigned short* __restrict__ Qb,
    const unsigned short* __restrict__ KVb,
    const float* __restrict__ Sf,
    const int* __restrict__ offsets,
    const int* __restrict__ counts,
    const int* __restrict__ ssrc,
    float* __restrict__ hout,
    unsigned short* __restrict__ Ahi,
    unsigned short* __restrict__ Alo) {
  int wv = threadIdx.x >> 6;
  int lane = threadIdx.x & 63;
  int i = blockIdx.x * 4 + wv;
  if (i >= N_NODES) return;

  const int off = (lane >> 4) * 64 + (lane & 15) * 4;

  ushort4 qb = *(const ushort4*)(Qb + (size_t)i * 256 + off);
  float4 q = make_float4(bf2f(qb.x), bf2f(qb.y), bf2f(qb.z), bf2f(qb.w));

  float mC[4] = {-1e30f, -1e30f, -1e30f, -1e30f};
  float sC[4] = {0.f, 0.f, 0.f, 0.f};
  float4 aC[4];
#pragma unroll
  for (int u = 0; u < 4; u++) aC[u] = make_float4(0.f, 0.f, 0.f, 0.f);

  const int beg = offsets[i];
  const int cnt = counts[i];
  int e = 0;
  for (; e + 4 <= cnt; e += 4) {
    int j[4];
#pragma unroll
    for (int u = 0; u < 4; u++) j[u] = ssrc[beg + e + u];
    ushort4 kk[4], vv[4];
#pragma unroll
    for (int u = 0; u < 4; u++) {
      const unsigned short* base = KVb + (size_t)j[u] * 512;
      kk[u] = *(const ushort4*)(base + off);
      vv[u] = *(const ushort4*)(base + 256 + off);
    }
    float p[4];
#pragma unroll
    for (int u = 0; u < 4; u++)
      p[u] = q.x * bf2f(kk[u].x) + q.y * bf2f(kk[u].y) +
             q.z * bf2f(kk[u].z) + q.w * bf2f(kk[u].w);
#pragma unroll
    for (int u = 0; u < 4; u++) p[u] += __shfl_xor(p[u], 1);
#pragma unroll
    for (int u = 0; u < 4; u++) p[u] += __shfl_xor(p[u], 2);
#pragma unroll
    for (int u = 0; u < 4; u++) p[u] += __shfl_xor(p[u], 4);
#pragma unroll
    for (int u = 0; u < 4; u++) p[u] += __shfl_xor(p[u], 8);
#pragma unroll
    for (int u = 0; u < 4; u++) {
      float pv = p[u] * ATT_SCALE;
      float mn = fmaxf(mC[u], pv);
      float c = __expf(mC[u] - mn);
      float w = __expf(pv - mn);
      sC[u] = sC[u] * c + w;
      aC[u].x = aC[u].x * c + w * bf2f(vv[u].x);
      aC[u].y = aC[u].y * c + w * bf2f(vv[u].y);
      aC[u].z = aC[u].z * c + w * bf2f(vv[u].z);
      aC[u].w = aC[u].w * c + w * bf2f(vv[u].w);
      mC[u] = mn;
    }
  }
  for (; e < cnt; e++) {
    int j1 = ssrc[beg + e];
    const unsigned short* base = KVb + (size_t)j1 * 512;
    ushort4 k1 = *(const ushort4*)(base + off);
    ushort4 v1 = *(const ushort4*)(base + 256 + off);
    float p1 = q.x * bf2f(k1.x) + q.y * bf2f(k1.y) + q.z * bf2f(k1.z) + q.w * bf2f(k1.w);
    p1 += __shfl_xor(p1, 1);
    p1 += __shfl_xor(p1, 2);
    p1 += __shfl_xor(p1, 4);
    p1 += __shfl_xor(p1, 8);
    p1 *= ATT_SCALE;
    float mn = fmaxf(mC[0], p1); float c = __expf(mC[0] - mn); float w = __expf(p1 - mn);
    sC[0] = sC[0] * c + w;
    aC[0].x = aC[0].x * c + w * bf2f(v1.x);
    aC[0].y = aC[0].y * c + w * bf2f(v1.y);
    aC[0].z = aC[0].z * c + w * bf2f(v1.z);
    aC[0].w = aC[0].w * c + w * bf2f(v1.w);
    mC[0] = mn;
  }

  // merge 4 chains (finite sentinels, no NaN path)
  float mm = fmaxf(fmaxf(mC[0], mC[1]), fmaxf(mC[2], mC[3]));
  float s = 0.f;
  float4 a = make_float4(0.f, 0.f, 0.f, 0.f);
#pragma unroll
  for (int u = 0; u < 4; u++) {
    float c = __expf(mC[u] - mm);
    s += sC[u] * c;
    a.x += aC[u].x * c;
    a.y += aC[u].y * c;
    a.z += aC[u].z * c;
    a.w += aC[u].w * c;
  }

  float4 sk = *(const float4*)(Sf + (size_t)i * 256 + off);
  float inv = 1.f / (s + 1e-16f);
  float4 o = make_float4(fmaxf(a.x * inv + sk.x, 0.f),
                         fmaxf(a.y * inv + sk.y, 0.f),
                         fmaxf(a.z * inv + sk.z, 0.f),
                         fmaxf(a.w * inv + sk.w, 0.f));
  if (MODE == 0) {
    *(float4*)(hout + (size_t)i * 256 + off) = o;
  } else {
    ushort4 hi, lo;
    hi.x = f2bf(o.x); lo.x = f2bf(o.x - bf2f(hi.x));
    hi.y = f2bf(o.y); lo.y = f2bf(o.y - bf2f(hi.y));
    hi.z = f2bf(o.z); lo.z = f2bf(o.z - bf2f(hi.z));
    hi.w = f2bf(o.w); lo.w = f2bf(o.w - bf2f(hi.w));
    *(ushort4*)(Ahi + (size_t)i * 256 + off) = hi;
    *(ushort4*)(Alo + (size_t)i * 256 + off) = lo;
  }
}

// ---------------------------------------------------------------- fp32 GEMM (fallback, proven)
#define BM 128
#define BN 128
#define BK 16
__global__ __launch_bounds__(256) void gemm_kernel(
    const float* __restrict__ X,
    const float* __restrict__ Wq, const float* __restrict__ Wk,
    const float* __restrict__ Wv, const float* __restrict__ Ws,
    const float* __restrict__ bq, const float* __restrict__ bk,
    const float* __restrict__ bv, const float* __restrict__ bs,
    int layer, float* __restrict__ out) {
  __shared__ __align__(16) float As[BK][BM + 4];
  __shared__ __align__(16) float Bs[BK][BN + 4];
  const int m0 = blockIdx.x * BM;
  const int n0 = blockIdx.y * BN;
  const int wsel = n0 >> 8;
  const float* W;
  const float* bias;
  if (wsel == 0)      { W = Wq; bias = bq; }
  else if (wsel == 1) { W = Wk; bias = bk; }
  else if (wsel == 2) { W = Wv; bias = bv; }
  else                { W = Ws; bias = bs; }
  W += (size_t)layer * 256 * 256;
  bias += (size_t)layer * 256;
  const int nc0 = n0 & 255;
  const int tid = threadIdx.x;
  const int tx = tid & 15;
  const int ty = tid >> 4;
  float acc[8][8];
#pragma unroll
  for (int i = 0; i < 8; i++)
#pragma unroll
    for (int j = 0; j < 8; j++) acc[i][j] = 0.f;
  for (int k0 = 0; k0 < 256; k0 += BK) {
#pragma unroll
    for (int i = 0; i < 8; i++) {
      int idx = tid + i * 256;
      int r = idx >> 4, c = idx & 15;
      int gr = m0 + r;
      As[c][r] = (gr < N_NODES) ? X[(size_t)gr * 256 + k0 + c] : 0.f;
    }
#pragma unroll
    for (int i = 0; i < 8; i++) {
      int idx = tid + i * 256;
      int r = idx >> 7, c = idx & 127;
      Bs[r][c] = W[(size_t)(k0 + r) * 256 + nc0 + c];
    }
    __syncthreads();
#pragma unroll
    for (int k = 0; k < BK; k++) {
      float4 a0 = *(const float4*)&As[k][ty * 8];
      float4 a1 = *(const float4*)&As[k][ty * 8 + 4];
      float4 b0 = *(const float4*)&Bs[k][tx * 8];
      float4 b1 = *(const float4*)&Bs[k][tx * 8 + 4];
      float a[8] = {a0.x, a0.y, a0.z, a0.w, a1.x, a1.y, a1.z, a1.w};
      float b[8] = {b0.x, b0.y, b0.z, b0.w, b1.x, b1.y, b1.z, b1.w};
#pragma unroll
      for (int mi = 0; mi < 8; mi++)
#pragma unroll
        for (int ni = 0; ni < 8; ni++) acc[mi][ni] = fmaf(a[mi], b[ni], acc[mi][ni]);
    }
    __syncthreads();
  }
  float bl[8];
#pragma unroll
  for (int ni = 0; ni < 8; ni++) bl[ni] = bias[nc0 + tx * 8 + ni];
#pragma unroll
  for (int mi = 0; mi < 8; mi++) {
    int row = m0 + ty * 8 + mi;
    if (row < N_NODES) {
      float* orow = out + (size_t)row * 1024 + n0 + tx * 8;
      float4 o0 = make_float4(acc[mi][0] + bl[0], acc[mi][1] + bl[1],
                              acc[mi][2] + bl[2], acc[mi][3] + bl[3]);
      float4 o1 = make_float4(acc[mi][4] + bl[4], acc[mi][5] + bl[5],
                              acc[mi][6] + bl[6], acc[mi][7] + bl[7]);
      *(float4*)orow = o0;
      *(float4*)(orow + 4) = o1;
    }
  }
}

// legacy attention over packed qkvs [N,1024] (fallback path)
__global__ __launch_bounds__(256) void attn_legacy(
    const float* __restrict__ qkvs,
    const int* __restrict__ offsets,
    const int* __restrict__ counts,
    const int* __restrict__ ssrc,
    float* __restrict__ hout) {
  int wv = threadIdx.x >> 6;
  int lane = threadIdx.x & 63;
  int i = blockIdx.x * 4 + wv;
  if (i >= N_NODES) return;
  const int off = (lane >> 4) * 64 + (lane & 15) * 4;
  const float* base_i = qkvs + (size_t)i * 1024;
  float4 q = *(const float4*)(base_i + off);
  float m = -INFINITY, s = 0.f;
  float4 a = make_float4(0.f, 0.f, 0.f, 0.f);
  int beg = offsets[i];
  int cnt = counts[i];
  for (int e = 0; e < cnt; e++) {
    int j = ssrc[beg + e];
    const float* base_j = qkvs + (size_t)j * 1024;
    float4 k = *(const float4*)(base_j + 256 + off);
    float p = q.x * k.x + q.y * k.y + q.z * k.z + q.w * k.w;
    p += __shfl_xor(p, 1);
    p += __shfl_xor(p, 2);
    p += __shfl_xor(p, 4);
    p += __shfl_xor(p, 8);
    p *= ATT_SCALE;
    float4 v = *(const float4*)(base_j + 512 + off);
    float mn = fmaxf(m, p);
    float c = __expf(m - mn);
    float w = __expf(p - mn);
    s = s * c + w;
    a.x = a.x * c + w * v.x;
    a.y = a.y * c + w * v.y;
    a.z = a.z * c + w * v.z;
    a.w = a.w * c + w * v.w;
    m = mn;
  }
  float4 sk = *(const float4*)(base_i + 768 + off);
  float inv = 1.f / (s + 1e-16f);
  float4 o = make_float4(fmaxf(a.x * inv + sk.x, 0.f),
                         fmaxf(a.y * inv + sk.y, 0.f),
                         fmaxf(a.z * inv + sk.z, 0.f),
                         fmaxf(a.w * inv + sk.w, 0.f));
  *(float4*)(hout + (size_t)i * 256 + off) = o;
}

// ---------------------------------------------------------------- launch
extern "C" void kernel_launch(void* const* d_in, const int* in_sizes, int n_in,
                              void* d_out, int out_size, void* d_ws, size_t ws_size,
                              hipStream_t stream) {
  (void)in_sizes; (void)n_in; (void)out_size;
  const float* x   = (const float*)d_in[0];
  const int*   ei  = (const int*)d_in[1];
  const float* Wq  = (const float*)d_in[2];
  const float* bq  = (const float*)d_in[3];
  const float* Wk  = (const float*)d_in[4];
  const float* bk  = (const float*)d_in[5];
  const float* Wv  = (const float*)d_in[6];
  const float* bv  = (const float*)d_in[7];
  const float* Ws_ = (const float*)d_in[8];
  const float* bs  = (const float*)d_in[9];
  float* out = (float*)d_out;

  const int* src = ei;
  const int* dst = ei + N_EDGES;
  char* ws = (char*)d_ws;

  // bf16-path workspace layout (bytes); total 187,768,064
  const size_t NEED = 187768064ull;
  bool big = ws_size >= NEED;

  if (big) {
    unsigned short* Qb   = (unsigned short*)(ws + 0);            //  25,600,000
    unsigned short* KVb  = (unsigned short*)(ws + 25600000);     //  51,200,000
    float*          Sf   = (float*)(ws + 76800000);              //  51,200,000
    unsigned short* Ahi  = (unsigned short*)(ws + 128000000);    //  25,624,576 (50048 rows)
    unsigned short* Alo  = (unsigned short*)(ws + 153624576);    //  25,624,576
    unsigned short* Bexp = (unsigned short*)(ws + 179249152);    //   4,718,592
    int* counts = (int*)(ws + 183967744);
    int* offs   = (int*)(ws + 184167744);
    int* cursor = (int*)(ws + 184367808);
    int* ssrc   = (int*)(ws + 184567808);                        //   3,200,000
    int* btot   = (int*)(ws + 187767808);                        //         256

    zero_int<<<(N_NODES + 255) / 256, 256, 0, stream>>>(counts, N_NODES);
    hist_kernel<<<(N_EDGES + 255) / 256, 256, 0, stream>>>(dst, counts, N_EDGES);
    scan1_kernel<<<(N_NODES + 1023) / 1024, 1024, 0, stream>>>(counts, offs, btot, N_NODES);
    scan2_kernel<<<1, 64, 0, stream>>>(btot, (N_NODES + 1023) / 1024);
    scan3_kernel<<<(N_NODES + 255) / 256, 256, 0, stream>>>(offs, cursor, btot, N_NODES);
    fill_kernel<<<(N_EDGES + 255) / 256, 256, 0, stream>>>(src, dst, cursor, ssrc, N_EDGES);
    sort_kernel<<<(N_NODES + 255) / 256, 256, 0, stream>>>(offs, counts, ssrc);

    convert_w_kernel<<<3072, 256, 0, stream>>>(Wq, Wk, Wv, Ws_, Bexp);
    convert_x_kernel<<<(N_NODES * 64 + 255) / 256, 256, 0, stream>>>(x, Ahi, Alo);

    for (int l = 0; l < 3; l++) {
      bgemm_kernel<<<3128, 256, 0, stream>>>(Ahi, Alo, Bexp, bq, bk, bv, bs, l, Qb, KVb, Sf);
      if (l < 2)
        attn_kernel<1><<<(N_NODES + 3) / 4, 256, 0, stream>>>(Qb, KVb, Sf, offs, counts, ssrc,
                                                              nullptr, Ahi, Alo);
      else
        attn_kernel<0><<<(N_NODES + 3) / 4, 256, 0, stream>>>(Qb, KVb, Sf, offs, counts, ssrc,
                                                              out, nullptr, nullptr);
    }
  } else {
    // fallback: proven fp32 path (round-2 layout)
    float* qkvs   = (float*)(ws + 0);
    float* hbuf   = (float*)(ws + 204800000);
    int*   counts = (int*)(ws + 256000000);
    int*   offs   = (int*)(ws + 256200064);
    int*   cursor = (int*)(ws + 256400128);
    int*   ssrc   = (int*)(ws + 256600192);

    zero_int<<<(N_NODES + 255) / 256, 256, 0, stream>>>(counts, N_NODES);
    hist_kernel<<<(N_EDGES + 255) / 256, 256, 0, stream>>>(dst, counts, N_EDGES);
    scan_kernel<<<1, 1024, 0, stream>>>(counts, offs, cursor, N_NODES);
    fill_kernel<<<(N_EDGES + 255) / 256, 256, 0, stream>>>(src, dst, cursor, ssrc, N_EDGES);

    dim3 ggrid((N_NODES + BM - 1) / BM, 1024 / BN);
    for (int l = 0; l < 3; l++) {
      const float* hin = (l == 0) ? x : hbuf;
      float* hout = (l == 2) ? out : hbuf;
      gemm_kernel<<<ggrid, 256, 0, stream>>>(hin, Wq, Wk, Wv, Ws_, bq, bk, bv, bs, l, qkvs);
      attn_legacy<<<(N_NODES + 3) / 4, 256, 0, stream>>>(qkvs, offs, counts, ssrc, hout);
    }
  }
}

// Round 9
// 827.796 us; speedup vs baseline: 1.0835x; 1.0835x over previous
//
#include <hip/hip_runtime.h>
#include <hip/hip_bf16.h>
#include <math.h>

#define N_NODES 50000
#define N_EDGES 800000
#define ATT_SCALE 0.125f    // 1/sqrt(64)

typedef __attribute__((ext_vector_type(8))) short bf16x8;
typedef __attribute__((ext_vector_type(4))) float f32x4;

__device__ __forceinline__ unsigned short f2bf(float f) {
  __hip_bfloat16 h = __float2bfloat16(f);
  unsigned short u; __builtin_memcpy(&u, &h, 2); return u;
}
__device__ __forceinline__ float bf2f(unsigned short u) {
  __hip_bfloat16 h; __builtin_memcpy(&h, &u, 2); return __bfloat162float(h);
}
__device__ __forceinline__ void gload16(const void* g, void* l) {
  __builtin_amdgcn_global_load_lds(
      (const __attribute__((address_space(1))) unsigned int*)g,
      (__attribute__((address_space(3))) unsigned int*)l, 16, 0, 0);
}

// ---------------------------------------------------------------- CSR build
__global__ void zero_int(int* __restrict__ p, int n) {
  int i = blockIdx.x * blockDim.x + threadIdx.x;
  if (i < n) p[i] = 0;
}

__global__ void hist_kernel(const int* __restrict__ dst, int* __restrict__ counts, int e) {
  int i = blockIdx.x * blockDim.x + threadIdx.x;
  if (i < e) atomicAdd(&counts[dst[i]], 1);
}

// parallel scan, stage 1: per-block (1024) local exclusive scan + block total
__global__ __launch_bounds__(1024) void scan1_kernel(const int* __restrict__ counts,
                                                     int* __restrict__ offsets,
                                                     int* __restrict__ btot, int n) {
  __shared__ int wsum[16];
  const int tid = threadIdx.x;
  const int lane = tid & 63, wid = tid >> 6;
  int idx = blockIdx.x * 1024 + tid;
  int v = (idx < n) ? counts[idx] : 0;
  int s = v;
#pragma unroll
  for (int off = 1; off < 64; off <<= 1) {
    int t = __shfl_up(s, off);
    if (lane >= off) s += t;
  }
  if (lane == 63) wsum[wid] = s;
  __syncthreads();
  if (wid == 0) {
    int wsv = (lane < 16) ? wsum[lane] : 0;
#pragma unroll
    for (int off = 1; off < 16; off <<= 1) {
      int t = __shfl_up(wsv, off);
      if (lane >= off) wsv += t;
    }
    if (lane < 16) wsum[lane] = wsv;
  }
  __syncthreads();
  int wbase = (wid > 0) ? wsum[wid - 1] : 0;
  if (idx < n) offsets[idx] = wbase + s - v;   // block-local exclusive
  if (tid == 0) btot[blockIdx.x] = wsum[15];
}

// stage 2: one wave exclusive-scans the <=64 block totals in place
__global__ __launch_bounds__(64) void scan2_kernel(int* __restrict__ btot, int nb) {
  int lane = threadIdx.x;
  int v = (lane < nb) ? btot[lane] : 0;
  int s = v;
#pragma unroll
  for (int off = 1; off < 64; off <<= 1) {
    int t = __shfl_up(s, off);
    if (lane >= off) s += t;
  }
  if (lane < nb) btot[lane] = s - v;
}

// stage 3: add block bases; write both offsets and cursor
__global__ void scan3_kernel(int* __restrict__ offsets, int* __restrict__ cursor,
                             const int* __restrict__ btot, int n) {
  int i = blockIdx.x * blockDim.x + threadIdx.x;
  if (i < n) {
    int o = offsets[i] + btot[i >> 10];
    offsets[i] = o;
    cursor[i] = o;
  }
}

// legacy single-block scan (fallback path only)
__global__ __launch_bounds__(1024) void scan_kernel(const int* __restrict__ counts,
                                                    int* __restrict__ offsets,
                                                    int* __restrict__ cursor, int n) {
  __shared__ int wsum[16];
  const int tid = threadIdx.x;
  const int lane = tid & 63, wid = tid >> 6;
  int carry = 0;
  for (int base = 0; base < n; base += 1024) {
    int idx = base + tid;
    int v = (idx < n) ? counts[idx] : 0;
    int s = v;
#pragma unroll
    for (int off = 1; off < 64; off <<= 1) {
      int t = __shfl_up(s, off);
      if (lane >= off) s += t;
    }
    if (lane == 63) wsum[wid] = s;
    __syncthreads();
    if (wid == 0) {
      int wsv = (lane < 16) ? wsum[lane] : 0;
#pragma unroll
      for (int off = 1; off < 16; off <<= 1) {
        int t = __shfl_up(wsv, off);
        if (lane >= off) wsv += t;
      }
      if (lane < 16) wsum[lane] = wsv;
    }
    __syncthreads();
    int wbase = (wid > 0) ? wsum[wid - 1] : 0;
    if (idx < n) {
      int ex = carry + wbase + s - v;
      offsets[idx] = ex;
      cursor[idx] = ex;
    }
    int total = wsum[15];
    __syncthreads();
    carry += total;
  }
  if (tid == 0) offsets[n] = carry;
}

__global__ void fill_kernel(const int* __restrict__ src, const int* __restrict__ dst,
                            int* __restrict__ cursor, int* __restrict__ ssrc, int e) {
  int i = blockIdx.x * blockDim.x + threadIdx.x;
  if (i < e) {
    int d = dst[i];
    int slot = atomicAdd(&cursor[d], 1);
    ssrc[slot] = src[i];
  }
}

// ---------------------------------------------------------------- converts
__global__ void convert_x_kernel(const float* __restrict__ x,
                                 unsigned short* __restrict__ Ahi,
                                 unsigned short* __restrict__ Alo) {
  int t = blockIdx.x * blockDim.x + threadIdx.x;   // N*64
  int row = t >> 6, g = (t & 63) * 4;
  if (row >= N_NODES) return;
  float4 xv = *(const float4*)(x + (size_t)row * 256 + g);
  ushort4 hi, lo;
  hi.x = f2bf(xv.x); lo.x = f2bf(xv.x - bf2f(hi.x));
  hi.y = f2bf(xv.y); lo.y = f2bf(xv.y - bf2f(hi.y));
  hi.z = f2bf(xv.z); lo.z = f2bf(xv.z - bf2f(hi.z));
  hi.w = f2bf(xv.w); lo.w = f2bf(xv.w - bf2f(hi.w));
  *(ushort4*)(Ahi + (size_t)row * 256 + g) = hi;
  *(ushort4*)(Alo + (size_t)row * 256 + g) = lo;
}

// Bexp[l][n][0:256]=hi(W[k][n]), [256:512]=lo, [512:768]=hi   (k-contiguous rows)
__global__ void convert_w_kernel(const float* __restrict__ Wq, const float* __restrict__ Wk,
                                 const float* __restrict__ Wv, const float* __restrict__ Ws,
                                 unsigned short* __restrict__ Bexp) {
  int t = blockIdx.x * blockDim.x + threadIdx.x;   // 3*256*1024
  if (t >= 3 * 256 * 1024) return;
  int n = t & 1023;
  int k = (t >> 10) & 255;
  int l = t >> 18;
  const float* W = (n < 256) ? Wq : (n < 512) ? Wk : (n < 768) ? Wv : Ws;
  float w = W[l * 65536 + k * 256 + (n & 255)];
  unsigned short hi = f2bf(w);
  unsigned short lo = f2bf(w - bf2f(hi));
  unsigned short* row = Bexp + ((size_t)l * 1024 + n) * 768;
  row[k] = hi; row[256 + k] = lo; row[512 + k] = hi;
}

// ---------------------------------------------------------------- bf16 MFMA GEMM
// logical out[N,1024] = [Q|K|V|S]; Q -> bf16 [N,256]; K,V interleaved KV [N,512]
// bf16 (K in cols 0:256, V in 256:512); S -> fp32 [N,256].
// Phase A: stage Ahi once with BOTH B slices -> 64 MFMA per barrier-pair.
// Phase B: Alo x W_hi. tile 128x128, 4 waves 2x2, mfma 16x16x32; XCD swizzle.
__global__ __launch_bounds__(256) void bgemm_kernel(
    const unsigned short* __restrict__ Ahi,   // [N(+pad)][256]
    const unsigned short* __restrict__ Alo,   // [N(+pad)][256]
    const unsigned short* __restrict__ B,     // [3][1024][768]
    const float* __restrict__ bq, const float* __restrict__ bk,
    const float* __restrict__ bv, const float* __restrict__ bs,
    int layer,
    unsigned short* __restrict__ Qb,          // [N][256] bf16
    unsigned short* __restrict__ KVb,         // [N][512] bf16 (K|V)
    float* __restrict__ Sf) {                 // [N][256] fp32
  __shared__ __align__(16) char lds[49152];
  char* Al  = lds;
  char* Bl1 = lds + 16384;
  char* Bl2 = lds + 32768;

  // XCD-aware swizzle (bijective: 3128 = 8*391)
  const int orig = blockIdx.x;
  const int swz = (orig & 7) * 391 + (orig >> 3);
  const int nb = swz & 7;                  // col block of 128 (fastest in-chunk)
  const int m0 = (swz >> 3) * 128;

  const int tid = threadIdx.x;
  const int wid = tid >> 6;
  const int lane = tid & 63;
  const int l15 = lane & 15, lhi = lane >> 4;
  const int wr = wid >> 1, wc = wid & 1;   // wave grid 2x2

  const char* Ag_hi = (const char*)Ahi;
  const char* Ag_lo = (const char*)Alo;
  const char* Bg = (const char*)(B + ((size_t)layer * 1024 + nb * 128) * 768);

  f32x4 acc[4][4];
#pragma unroll
  for (int m = 0; m < 4; m++)
#pragma unroll
    for (int n = 0; n < 4; n++) acc[m][n] = (f32x4){0.f, 0.f, 0.f, 0.f};

  const int swzl = (l15 & 7) << 4;

  // ---- phase A: Ahi x (W_hi | W_lo) -------------------------------------
  for (int kt4 = 0; kt4 < 4; kt4++) {
    const int ka2 = kt4 * 128;           // byte offset of 64-k chunk in 512B row
#pragma unroll
    for (int i = 0; i < 4; i++) {
      int o = tid * 16 + i * 4096;
      int row = o >> 7;
      int sg = ((o >> 4) & 7) ^ (row & 7);
      gload16(Ag_hi + (size_t)(m0 + row) * 512 + ka2 + sg * 16, Al  + wid * 1024 + i * 4096);
      gload16(Bg + (size_t)row * 1536 + ka2 + sg * 16,          Bl1 + wid * 1024 + i * 4096);
      gload16(Bg + (size_t)row * 1536 + 512 + ka2 + sg * 16,    Bl2 + wid * 1024 + i * 4096);
    }
    __syncthreads();

    bf16x8 af[2][4], bfrag[2][4];
#pragma unroll
    for (int kk = 0; kk < 2; kk++)
#pragma unroll
      for (int m = 0; m < 4; m++) {
        af[kk][m]    = *(const bf16x8*)(Al  + (wr * 64 + m * 16 + l15) * 128 + ((kk * 64 + lhi * 16) ^ swzl));
        bfrag[kk][m] = *(const bf16x8*)(Bl1 + (wc * 64 + m * 16 + l15) * 128 + ((kk * 64 + lhi * 16) ^ swzl));
      }
#pragma unroll
    for (int kk = 0; kk < 2; kk++)
#pragma unroll
      for (int m = 0; m < 4; m++)
#pragma unroll
        for (int n = 0; n < 4; n++)
          acc[m][n] = __builtin_amdgcn_mfma_f32_16x16x32_bf16(af[kk][m], bfrag[kk][n], acc[m][n], 0, 0, 0);
#pragma unroll
    for (int kk = 0; kk < 2; kk++)
#pragma unroll
      for (int m = 0; m < 4; m++)
        bfrag[kk][m] = *(const bf16x8*)(Bl2 + (wc * 64 + m * 16 + l15) * 128 + ((kk * 64 + lhi * 16) ^ swzl));
#pragma unroll
    for (int kk = 0; kk < 2; kk++)
#pragma unroll
      for (int m = 0; m < 4; m++)
#pragma unroll
        for (int n = 0; n < 4; n++)
          acc[m][n] = __builtin_amdgcn_mfma_f32_16x16x32_bf16(af[kk][m], bfrag[kk][n], acc[m][n], 0, 0, 0);
    __syncthreads();
  }

  // ---- phase B: Alo x W_hi (rows 512+k) ---------------------------------
  for (int kt4 = 0; kt4 < 4; kt4++) {
    const int ka2 = kt4 * 128;
#pragma unroll
    for (int i = 0; i < 4; i++) {
      int o = tid * 16 + i * 4096;
      int row = o >> 7;
      int sg = ((o >> 4) & 7) ^ (row & 7);
      gload16(Ag_lo + (size_t)(m0 + row) * 512 + ka2 + sg * 16, Al  + wid * 1024 + i * 4096);
      gload16(Bg + (size_t)row * 1536 + 1024 + ka2 + sg * 16,   Bl1 + wid * 1024 + i * 4096);
    }
    __syncthreads();

    bf16x8 af[2][4], bfrag[2][4];
#pragma unroll
    for (int kk = 0; kk < 2; kk++)
#pragma unroll
      for (int m = 0; m < 4; m++) {
        af[kk][m]    = *(const bf16x8*)(Al  + (wr * 64 + m * 16 + l15) * 128 + ((kk * 64 + lhi * 16) ^ swzl));
        bfrag[kk][m] = *(const bf16x8*)(Bl1 + (wc * 64 + m * 16 + l15) * 128 + ((kk * 64 + lhi * 16) ^ swzl));
      }
#pragma unroll
    for (int kk = 0; kk < 2; kk++)
#pragma unroll
      for (int m = 0; m < 4; m++)
#pragma unroll
        for (int n = 0; n < 4; n++)
          acc[m][n] = __builtin_amdgcn_mfma_f32_16x16x32_bf16(af[kk][m], bfrag[kk][n], acc[m][n], 0, 0, 0);
    __syncthreads();
  }

  // ---- epilogue ---------------------------------------------------------
  const float* bias = ((nb < 2) ? bq : (nb < 4) ? bk : (nb < 6) ? bv : bs) + layer * 256 + (nb & 1) * 128;
  float bn[4];
#pragma unroll
  for (int n = 0; n < 4; n++) bn[n] = bias[wc * 64 + n * 16 + l15];

  const int col = (nb & 1) * 128 + wc * 64 + l15;
  if (nb < 2) {
#pragma unroll
    for (int m = 0; m < 4; m++) {
#pragma unroll
      for (int r = 0; r < 4; r++) {
        int row = m0 + wr * 64 + m * 16 + lhi * 4 + r;
        if (row < N_NODES) {
          unsigned short* orow = Qb + (size_t)row * 256 + col;
#pragma unroll
          for (int n = 0; n < 4; n++) orow[n * 16] = f2bf(acc[m][n][r] + bn[n]);
        }
      }
    }
  } else if (nb < 6) {
    const int col512 = ((nb >= 4) ? 256 : 0) + col;   // K in [0,256), V in [256,512)
#pragma unroll
    for (int m = 0; m < 4; m++) {
#pragma unroll
      for (int r = 0; r < 4; r++) {
        int row = m0 + wr * 64 + m * 16 + lhi * 4 + r;
        if (row < N_NODES) {
          unsigned short* orow = KVb + (size_t)row * 512 + col512;
#pragma unroll
          for (int n = 0; n < 4; n++) orow[n * 16] = f2bf(acc[m][n][r] + bn[n]);
        }
      }
    }
  } else {
#pragma unroll
    for (int m = 0; m < 4; m++) {
#pragma unroll
      for (int r = 0; r < 4; r++) {
        int row = m0 + wr * 64 + m * 16 + lhi * 4 + r;
        if (row < N_NODES) {
          float* orow = Sf + (size_t)row * 256 + col;
#pragma unroll
          for (int n = 0; n < 4; n++) orow[n * 16] = acc[m][n][r] + bn[n];
        }
      }
    }
  }
}

// ---------------------------------------------------------------- attention
// one wave per dst node; lane l: head l>>4, channels (l&15)*4..+3.
// Q bf16 [N,256]; KV bf16 [N,512]; S fp32 [N,256]. 4-edge batched loads,
// single (m,s,a) online-softmax state with T13 defer-max (RESCALE_THR=8):
// rescale only when a block's max exceeds m+8; common path = 1 exp/edge.
// MODE 0: write fp32 [N,256] to hout. MODE 1: write split-bf16 Ahi/Alo.
template <int MODE>
__global__ __launch_bounds__(256) void attn_kernel(
    const unsigned short* __restrict__ Qb,
    const unsigned short* __restrict__ KVb,
    const float* __restrict__ Sf,
    const int* __restrict__ offsets,
    const int* __restrict__ counts,
    const int* __restrict__ ssrc,
    float* __restrict__ hout,
    unsigned short* __restrict__ Ahi,
    unsigned short* __restrict__ Alo) {
  int wv = threadIdx.x >> 6;
  int lane = threadIdx.x & 63;
  int i = blockIdx.x * 4 + wv;
  if (i >= N_NODES) return;

  const int off = (lane >> 4) * 64 + (lane & 15) * 4;

  ushort4 qb = *(const ushort4*)(Qb + (size_t)i * 256 + off);
  float4 q = make_float4(bf2f(qb.x), bf2f(qb.y), bf2f(qb.z), bf2f(qb.w));

  float m = -1e30f, s = 0.f;
  float4 a = make_float4(0.f, 0.f, 0.f, 0.f);

  const int beg = offsets[i];
  const int cnt = counts[i];
  int e = 0;
  for (; e + 4 <= cnt; e += 4) {
    int j[4];
#pragma unroll
    for (int u = 0; u < 4; u++) j[u] = ssrc[beg + e + u];
    ushort4 kk[4], vv[4];
#pragma unroll
    for (int u = 0; u < 4; u++) {
      const unsigned short* base = KVb + (size_t)j[u] * 512;
      kk[u] = *(const ushort4*)(base + off);
      vv[u] = *(const ushort4*)(base + 256 + off);
    }
    float p[4];
#pragma unroll
    for (int u = 0; u < 4; u++)
      p[u] = q.x * bf2f(kk[u].x) + q.y * bf2f(kk[u].y) +
             q.z * bf2f(kk[u].z) + q.w * bf2f(kk[u].w);
#pragma unroll
    for (int u = 0; u < 4; u++) p[u] += __shfl_xor(p[u], 1);
#pragma unroll
    for (int u = 0; u < 4; u++) p[u] += __shfl_xor(p[u], 2);
#pragma unroll
    for (int u = 0; u < 4; u++) p[u] += __shfl_xor(p[u], 4);
#pragma unroll
    for (int u = 0; u < 4; u++) p[u] += __shfl_xor(p[u], 8);
#pragma unroll
    for (int u = 0; u < 4; u++) p[u] *= ATT_SCALE;

    // T13 defer-max: rescale only if some head's block max exceeds m+8
    float bm = fmaxf(fmaxf(p[0], p[1]), fmaxf(p[2], p[3]));
    if (!__all(bm <= m + 8.f)) {
      float mn = fmaxf(m, bm);
      float c = __expf(m - mn);
      s *= c; a.x *= c; a.y *= c; a.z *= c; a.w *= c;
      m = mn;
    }
#pragma unroll
    for (int u = 0; u < 4; u++) {
      float w = __expf(p[u] - m);
      s += w;
      a.x += w * bf2f(vv[u].x);
      a.y += w * bf2f(vv[u].y);
      a.z += w * bf2f(vv[u].z);
      a.w += w * bf2f(vv[u].w);
    }
  }
  for (; e < cnt; e++) {
    int j1 = ssrc[beg + e];
    const unsigned short* base = KVb + (size_t)j1 * 512;
    ushort4 k1 = *(const ushort4*)(base + off);
    ushort4 v1 = *(const ushort4*)(base + 256 + off);
    float p1 = q.x * bf2f(k1.x) + q.y * bf2f(k1.y) + q.z * bf2f(k1.z) + q.w * bf2f(k1.w);
    p1 += __shfl_xor(p1, 1);
    p1 += __shfl_xor(p1, 2);
    p1 += __shfl_xor(p1, 4);
    p1 += __shfl_xor(p1, 8);
    p1 *= ATT_SCALE;
    if (!__all(p1 <= m + 8.f)) {
      float mn = fmaxf(m, p1);
      float c = __expf(m - mn);
      s *= c; a.x *= c; a.y *= c; a.z *= c; a.w *= c;
      m = mn;
    }
    float w = __expf(p1 - m);
    s += w;
    a.x += w * bf2f(v1.x);
    a.y += w * bf2f(v1.y);
    a.z += w * bf2f(v1.z);
    a.w += w * bf2f(v1.w);
  }

  float4 sk = *(const float4*)(Sf + (size_t)i * 256 + off);
  float inv = 1.f / (s + 1e-16f);
  float4 o = make_float4(fmaxf(a.x * inv + sk.x, 0.f),
                         fmaxf(a.y * inv + sk.y, 0.f),
                         fmaxf(a.z * inv + sk.z, 0.f),
                         fmaxf(a.w * inv + sk.w, 0.f));
  if (MODE == 0) {
    *(float4*)(hout + (size_t)i * 256 + off) = o;
  } else {
    ushort4 hi, lo;
    hi.x = f2bf(o.x); lo.x = f2bf(o.x - bf2f(hi.x));
    hi.y = f2bf(o.y); lo.y = f2bf(o.y - bf2f(hi.y));
    hi.z = f2bf(o.z); lo.z = f2bf(o.z - bf2f(hi.z));
    hi.w = f2bf(o.w); lo.w = f2bf(o.w - bf2f(hi.w));
    *(ushort4*)(Ahi + (size_t)i * 256 + off) = hi;
    *(ushort4*)(Alo + (size_t)i * 256 + off) = lo;
  }
}

// ---------------------------------------------------------------- fp32 GEMM (fallback, proven)
#define BM 128
#define BN 128
#define BK 16
__global__ __launch_bounds__(256) void gemm_kernel(
    const float* __restrict__ X,
    const float* __restrict__ Wq, const float* __restrict__ Wk,
    const float* __restrict__ Wv, const float* __restrict__ Ws,
    const float* __restrict__ bq, const float* __restrict__ bk,
    const float* __restrict__ bv, const float* __restrict__ bs,
    int layer, float* __restrict__ out) {
  __shared__ __align__(16) float As[BK][BM + 4];
  __shared__ __align__(16) float Bs[BK][BN + 4];
  const int m0 = blockIdx.x * BM;
  const int n0 = blockIdx.y * BN;
  const int wsel = n0 >> 8;
  const float* W;
  const float* bias;
  if (wsel == 0)      { W = Wq; bias = bq; }
  else if (wsel == 1) { W = Wk; bias = bk; }
  else if (wsel == 2) { W = Wv; bias = bv; }
  else                { W = Ws; bias = bs; }
  W += (size_t)layer * 256 * 256;
  bias += (size_t)layer * 256;
  const int nc0 = n0 & 255;
  const int tid = threadIdx.x;
  const int tx = tid & 15;
  const int ty = tid >> 4;
  float acc[8][8];
#pragma unroll
  for (int i = 0; i < 8; i++)
#pragma unroll
    for (int j = 0; j < 8; j++) acc[i][j] = 0.f;
  for (int k0 = 0; k0 < 256; k0 += BK) {
#pragma unroll
    for (int i = 0; i < 8; i++) {
      int idx = tid + i * 256;
      int r = idx >> 4, c = idx & 15;
      int gr = m0 + r;
      As[c][r] = (gr < N_NODES) ? X[(size_t)gr * 256 + k0 + c] : 0.f;
    }
#pragma unroll
    for (int i = 0; i < 8; i++) {
      int idx = tid + i * 256;
      int r = idx >> 7, c = idx & 127;
      Bs[r][c] = W[(size_t)(k0 + r) * 256 + nc0 + c];
    }
    __syncthreads();
#pragma unroll
    for (int k = 0; k < BK; k++) {
      float4 a0 = *(const float4*)&As[k][ty * 8];
      float4 a1 = *(const float4*)&As[k][ty * 8 + 4];
      float4 b0 = *(const float4*)&Bs[k][tx * 8];
      float4 b1 = *(const float4*)&Bs[k][tx * 8 + 4];
      float a[8] = {a0.x, a0.y, a0.z, a0.w, a1.x, a1.y, a1.z, a1.w};
      float b[8] = {b0.x, b0.y, b0.z, b0.w, b1.x, b1.y, b1.z, b1.w};
#pragma unroll
      for (int mi = 0; mi < 8; mi++)
#pragma unroll
        for (int ni = 0; ni < 8; ni++) acc[mi][ni] = fmaf(a[mi], b[ni], acc[mi][ni]);
    }
    __syncthreads();
  }
  float bl[8];
#pragma unroll
  for (int ni = 0; ni < 8; ni++) bl[ni] = bias[nc0 + tx * 8 + ni];
#pragma unroll
  for (int mi = 0; mi < 8; mi++) {
    int row = m0 + ty * 8 + mi;
    if (row < N_NODES) {
      float* orow = out + (size_t)row * 1024 + n0 + tx * 8;
      float4 o0 = make_float4(acc[mi][0] + bl[0], acc[mi][1] + bl[1],
                              acc[mi][2] + bl[2], acc[mi][3] + bl[3]);
      float4 o1 = make_float4(acc[mi][4] + bl[4], acc[mi][5] + bl[5],
                              acc[mi][6] + bl[6], acc[mi][7] + bl[7]);
      *(float4*)orow = o0;
      *(float4*)(orow + 4) = o1;
    }
  }
}

// legacy attention over packed qkvs [N,1024] (fallback path)
__global__ __launch_bounds__(256) void attn_legacy(
    const float* __restrict__ qkvs,
    const int* __restrict__ offsets,
    const int* __restrict__ counts,
    const int* __restrict__ ssrc,
    float* __restrict__ hout) {
  int wv = threadIdx.x >> 6;
  int lane = threadIdx.x & 63;
  int i = blockIdx.x * 4 + wv;
  if (i >= N_NODES) return;
  const int off = (lane >> 4) * 64 + (lane & 15) * 4;
  const float* base_i = qkvs + (size_t)i * 1024;
  float4 q = *(const float4*)(base_i + off);
  float m = -INFINITY, s = 0.f;
  float4 a = make_float4(0.f, 0.f, 0.f, 0.f);
  int beg = offsets[i];
  int cnt = counts[i];
  for (int e = 0; e < cnt; e++) {
    int j = ssrc[beg + e];
    const float* base_j = qkvs + (size_t)j * 1024;
    float4 k = *(const float4*)(base_j + 256 + off);
    float p = q.x * k.x + q.y * k.y + q.z * k.z + q.w * k.w;
    p += __shfl_xor(p, 1);
    p += __shfl_xor(p, 2);
    p += __shfl_xor(p, 4);
    p += __shfl_xor(p, 8);
    p *= ATT_SCALE;
    float4 v = *(const float4*)(base_j + 512 + off);
    float mn = fmaxf(m, p);
    float c = __expf(m - mn);
    float w = __expf(p - mn);
    s = s * c + w;
    a.x = a.x * c + w * v.x;
    a.y = a.y * c + w * v.y;
    a.z = a.z * c + w * v.z;
    a.w = a.w * c + w * v.w;
    m = mn;
  }
  float4 sk = *(const float4*)(base_i + 768 + off);
  float inv = 1.f / (s + 1e-16f);
  float4 o = make_float4(fmaxf(a.x * inv + sk.x, 0.f),
                         fmaxf(a.y * inv + sk.y, 0.f),
                         fmaxf(a.z * inv + sk.z, 0.f),
                         fmaxf(a.w * inv + sk.w, 0.f));
  *(float4*)(hout + (size_t)i * 256 + off) = o;
}

// ---------------------------------------------------------------- launch
extern "C" void kernel_launch(void* const* d_in, const int* in_sizes, int n_in,
                              void* d_out, int out_size, void* d_ws, size_t ws_size,
                              hipStream_t stream) {
  (void)in_sizes; (void)n_in; (void)out_size;
  const float* x   = (const float*)d_in[0];
  const int*   ei  = (const int*)d_in[1];
  const float* Wq  = (const float*)d_in[2];
  const float* bq  = (const float*)d_in[3];
  const float* Wk  = (const float*)d_in[4];
  const float* bk  = (const float*)d_in[5];
  const float* Wv  = (const float*)d_in[6];
  const float* bv  = (const float*)d_in[7];
  const float* Ws_ = (const float*)d_in[8];
  const float* bs  = (const float*)d_in[9];
  float* out = (float*)d_out;

  const int* src = ei;
  const int* dst = ei + N_EDGES;
  char* ws = (char*)d_ws;

  // bf16-path workspace layout (bytes); total 187,768,064
  const size_t NEED = 187768064ull;
  bool big = ws_size >= NEED;

  if (big) {
    unsigned short* Qb   = (unsigned short*)(ws + 0);            //  25,600,000
    unsigned short* KVb  = (unsigned short*)(ws + 25600000);     //  51,200,000
    float*          Sf   = (float*)(ws + 76800000);              //  51,200,000
    unsigned short* Ahi  = (unsigned short*)(ws + 128000000);    //  25,624,576 (50048 rows)
    unsigned short* Alo  = (unsigned short*)(ws + 153624576);    //  25,624,576
    unsigned short* Bexp = (unsigned short*)(ws + 179249152);    //   4,718,592
    int* counts = (int*)(ws + 183967744);
    int* offs   = (int*)(ws + 184167744);
    int* cursor = (int*)(ws + 184367808);
    int* ssrc   = (int*)(ws + 184567808);                        //   3,200,000
    int* btot   = (int*)(ws + 187767808);                        //         256

    zero_int<<<(N_NODES + 255) / 256, 256, 0, stream>>>(counts, N_NODES);
    hist_kernel<<<(N_EDGES + 255) / 256, 256, 0, stream>>>(dst, counts, N_EDGES);
    scan1_kernel<<<(N_NODES + 1023) / 1024, 1024, 0, stream>>>(counts, offs, btot, N_NODES);
    scan2_kernel<<<1, 64, 0, stream>>>(btot, (N_NODES + 1023) / 1024);
    scan3_kernel<<<(N_NODES + 255) / 256, 256, 0, stream>>>(offs, cursor, btot, N_NODES);
    fill_kernel<<<(N_EDGES + 255) / 256, 256, 0, stream>>>(src, dst, cursor, ssrc, N_EDGES);

    convert_w_kernel<<<3072, 256, 0, stream>>>(Wq, Wk, Wv, Ws_, Bexp);
    convert_x_kernel<<<(N_NODES * 64 + 255) / 256, 256, 0, stream>>>(x, Ahi, Alo);

    for (int l = 0; l < 3; l++) {
      bgemm_kernel<<<3128, 256, 0, stream>>>(Ahi, Alo, Bexp, bq, bk, bv, bs, l, Qb, KVb, Sf);
      if (l < 2)
        attn_kernel<1><<<(N_NODES + 3) / 4, 256, 0, stream>>>(Qb, KVb, Sf, offs, counts, ssrc,
                                                              nullptr, Ahi, Alo);
      else
        attn_kernel<0><<<(N_NODES + 3) / 4, 256, 0, stream>>>(Qb, KVb, Sf, offs, counts, ssrc,
                                                              out, nullptr, nullptr);
    }
  } else {
    // fallback: proven fp32 path (round-2 layout)
    float* qkvs   = (float*)(ws + 0);
    float* hbuf   = (float*)(ws + 204800000);
    int*   counts = (int*)(ws + 256000000);
    int*   offs   = (int*)(ws + 256200064);
    int*   cursor = (int*)(ws + 256400128);
    int*   ssrc   = (int*)(ws + 256600192);

    zero_int<<<(N_NODES + 255) / 256, 256, 0, stream>>>(counts, N_NODES);
    hist_kernel<<<(N_EDGES + 255) / 256, 256, 0, stream>>>(dst, counts, N_EDGES);
    scan_kernel<<<1, 1024, 0, stream>>>(counts, offs, cursor, N_NODES);
    fill_kernel<<<(N_EDGES + 255) / 256, 256, 0, stream>>>(src, dst, cursor, ssrc, N_EDGES);

    dim3 ggrid((N_NODES + BM - 1) / BM, 1024 / BN);
    for (int l = 0; l < 3; l++) {
      const float* hin = (l == 0) ? x : hbuf;
      float* hout = (l == 2) ? out : hbuf;
      gemm_kernel<<<ggrid, 256, 0, stream>>>(hin, Wq, Wk, Wv, Ws_, bq, bk, bv, bs, l, qkvs);
      attn_legacy<<<(N_NODES + 3) / 4, 256, 0, stream>>>(qkvs, offs, counts, ssrc, hout);
    }
  }
}

// Round 10
// 784.525 us; speedup vs baseline: 1.1432x; 1.0552x over previous
//
#include <hip/hip_runtime.h>
#include <hip/hip_bf16.h>
#include <math.h>

#define N_NODES 50000
#define N_EDGES 800000
#define ATT_SCALE 0.125f    // 1/sqrt(64)

typedef __attribute__((ext_vector_type(8))) short bf16x8;
typedef __attribute__((ext_vector_type(4))) float f32x4;

__device__ __forceinline__ unsigned short f2bf(float f) {
  __hip_bfloat16 h = __float2bfloat16(f);
  unsigned short u; __builtin_memcpy(&u, &h, 2); return u;
}
__device__ __forceinline__ float bf2f(unsigned short u) {
  __hip_bfloat16 h; __builtin_memcpy(&h, &u, 2); return __bfloat162float(h);
}
__device__ __forceinline__ void gload16(const void* g, void* l) {
  __builtin_amdgcn_global_load_lds(
      (const __attribute__((address_space(1))) unsigned int*)g,
      (__attribute__((address_space(3))) unsigned int*)l, 16, 0, 0);
}

// ---------------------------------------------------------------- CSR build
__global__ void zero_int(int* __restrict__ p, int n) {
  int i = blockIdx.x * blockDim.x + threadIdx.x;
  if (i < n) p[i] = 0;
}

__global__ void hist_kernel(const int* __restrict__ dst, int* __restrict__ counts, int e) {
  int i = blockIdx.x * blockDim.x + threadIdx.x;
  if (i < e) atomicAdd(&counts[dst[i]], 1);
}

// parallel scan, stage 1: per-block (1024) local exclusive scan + block total
__global__ __launch_bounds__(1024) void scan1_kernel(const int* __restrict__ counts,
                                                     int* __restrict__ offsets,
                                                     int* __restrict__ btot, int n) {
  __shared__ int wsum[16];
  const int tid = threadIdx.x;
  const int lane = tid & 63, wid = tid >> 6;
  int idx = blockIdx.x * 1024 + tid;
  int v = (idx < n) ? counts[idx] : 0;
  int s = v;
#pragma unroll
  for (int off = 1; off < 64; off <<= 1) {
    int t = __shfl_up(s, off);
    if (lane >= off) s += t;
  }
  if (lane == 63) wsum[wid] = s;
  __syncthreads();
  if (wid == 0) {
    int wsv = (lane < 16) ? wsum[lane] : 0;
#pragma unroll
    for (int off = 1; off < 16; off <<= 1) {
      int t = __shfl_up(wsv, off);
      if (lane >= off) wsv += t;
    }
    if (lane < 16) wsum[lane] = wsv;
  }
  __syncthreads();
  int wbase = (wid > 0) ? wsum[wid - 1] : 0;
  if (idx < n) offsets[idx] = wbase + s - v;   // block-local exclusive
  if (tid == 0) btot[blockIdx.x] = wsum[15];
}

// stage 2: one wave exclusive-scans the <=64 block totals in place
__global__ __launch_bounds__(64) void scan2_kernel(int* __restrict__ btot, int nb) {
  int lane = threadIdx.x;
  int v = (lane < nb) ? btot[lane] : 0;
  int s = v;
#pragma unroll
  for (int off = 1; off < 64; off <<= 1) {
    int t = __shfl_up(s, off);
    if (lane >= off) s += t;
  }
  if (lane < nb) btot[lane] = s - v;
}

// stage 3: add block bases; write both offsets and cursor
__global__ void scan3_kernel(int* __restrict__ offsets, int* __restrict__ cursor,
                             const int* __restrict__ btot, int n) {
  int i = blockIdx.x * blockDim.x + threadIdx.x;
  if (i < n) {
    int o = offsets[i] + btot[i >> 10];
    offsets[i] = o;
    cursor[i] = o;
  }
}

// legacy single-block scan (fallback path only)
__global__ __launch_bounds__(1024) void scan_kernel(const int* __restrict__ counts,
                                                    int* __restrict__ offsets,
                                                    int* __restrict__ cursor, int n) {
  __shared__ int wsum[16];
  const int tid = threadIdx.x;
  const int lane = tid & 63, wid = tid >> 6;
  int carry = 0;
  for (int base = 0; base < n; base += 1024) {
    int idx = base + tid;
    int v = (idx < n) ? counts[idx] : 0;
    int s = v;
#pragma unroll
    for (int off = 1; off < 64; off <<= 1) {
      int t = __shfl_up(s, off);
      if (lane >= off) s += t;
    }
    if (lane == 63) wsum[wid] = s;
    __syncthreads();
    if (wid == 0) {
      int wsv = (lane < 16) ? wsum[lane] : 0;
#pragma unroll
      for (int off = 1; off < 16; off <<= 1) {
        int t = __shfl_up(wsv, off);
        if (lane >= off) wsv += t;
      }
      if (lane < 16) wsum[lane] = wsv;
    }
    __syncthreads();
    int wbase = (wid > 0) ? wsum[wid - 1] : 0;
    if (idx < n) {
      int ex = carry + wbase + s - v;
      offsets[idx] = ex;
      cursor[idx] = ex;
    }
    int total = wsum[15];
    __syncthreads();
    carry += total;
  }
  if (tid == 0) offsets[n] = carry;
}

__global__ void fill_kernel(const int* __restrict__ src, const int* __restrict__ dst,
                            int* __restrict__ cursor, int* __restrict__ ssrc, int e) {
  int i = blockIdx.x * blockDim.x + threadIdx.x;
  if (i < e) {
    int d = dst[i];
    int slot = atomicAdd(&cursor[d], 1);
    ssrc[slot] = src[i];
  }
}

// ---------------------------------------------------------------- converts
__global__ void convert_x_kernel(const float* __restrict__ x,
                                 unsigned short* __restrict__ Ahi,
                                 unsigned short* __restrict__ Alo) {
  int t = blockIdx.x * blockDim.x + threadIdx.x;   // N*64
  int row = t >> 6, g = (t & 63) * 4;
  if (row >= N_NODES) return;
  float4 xv = *(const float4*)(x + (size_t)row * 256 + g);
  ushort4 hi, lo;
  hi.x = f2bf(xv.x); lo.x = f2bf(xv.x - bf2f(hi.x));
  hi.y = f2bf(xv.y); lo.y = f2bf(xv.y - bf2f(hi.y));
  hi.z = f2bf(xv.z); lo.z = f2bf(xv.z - bf2f(hi.z));
  hi.w = f2bf(xv.w); lo.w = f2bf(xv.w - bf2f(hi.w));
  *(ushort4*)(Ahi + (size_t)row * 256 + g) = hi;
  *(ushort4*)(Alo + (size_t)row * 256 + g) = lo;
}

// Bexp[l][n][0:256]=hi(W[k][n]), [256:512]=lo, [512:768]=hi   (k-contiguous rows)
__global__ void convert_w_kernel(const float* __restrict__ Wq, const float* __restrict__ Wk,
                                 const float* __restrict__ Wv, const float* __restrict__ Ws,
                                 unsigned short* __restrict__ Bexp) {
  int t = blockIdx.x * blockDim.x + threadIdx.x;   // 3*256*1024
  if (t >= 3 * 256 * 1024) return;
  int n = t & 1023;
  int k = (t >> 10) & 255;
  int l = t >> 18;
  const float* W = (n < 256) ? Wq : (n < 512) ? Wk : (n < 768) ? Wv : Ws;
  float w = W[l * 65536 + k * 256 + (n & 255)];
  unsigned short hi = f2bf(w);
  unsigned short lo = f2bf(w - bf2f(hi));
  unsigned short* row = Bexp + ((size_t)l * 1024 + n) * 768;
  row[k] = hi; row[256 + k] = lo; row[512 + k] = hi;
}

// ---------------------------------------------------------------- bf16 MFMA GEMM
// logical out[N,1024] = [Q|K|V|S]; Q -> bf16 [N,256]; K,V interleaved KV [N,512]
// bf16; S -> fp32 [N,256].
// PRECISION-MATCHED WORK: Q/K/V cols (nb<6) are rounded to bf16 anyway, so
// hi x hi (K=256) suffices — error ~2^-9, same order as the output rounding.
// Only S (fp32 residual, compounds across layers) uses the 3-term K=768 split.
// tile 128x128, 4 waves 2x2, mfma 16x16x32; XCD-swizzled 1-D grid.
__global__ __launch_bounds__(256) void bgemm_kernel(
    const unsigned short* __restrict__ Ahi,   // [N(+pad)][256]
    const unsigned short* __restrict__ Alo,   // [N(+pad)][256]
    const unsigned short* __restrict__ B,     // [3][1024][768]
    const float* __restrict__ bq, const float* __restrict__ bk,
    const float* __restrict__ bv, const float* __restrict__ bs,
    int layer,
    unsigned short* __restrict__ Qb,          // [N][256] bf16
    unsigned short* __restrict__ KVb,         // [N][512] bf16 (K|V)
    float* __restrict__ Sf) {                 // [N][256] fp32
  __shared__ __align__(16) char lds[49152];
  char* Al  = lds;
  char* Bl1 = lds + 16384;
  char* Bl2 = lds + 32768;

  // XCD-aware swizzle (bijective: 3128 = 8*391)
  const int orig = blockIdx.x;
  const int swz = (orig & 7) * 391 + (orig >> 3);
  const int nb = swz & 7;                  // col block of 128 (fastest in-chunk)
  const int m0 = (swz >> 3) * 128;
  const bool full = (nb >= 6);             // S block -> full 3-term split

  const int tid = threadIdx.x;
  const int wid = tid >> 6;
  const int lane = tid & 63;
  const int l15 = lane & 15, lhi = lane >> 4;
  const int wr = wid >> 1, wc = wid & 1;   // wave grid 2x2

  const char* Ag_hi = (const char*)Ahi;
  const char* Ag_lo = (const char*)Alo;
  const char* Bg = (const char*)(B + ((size_t)layer * 1024 + nb * 128) * 768);

  f32x4 acc[4][4];
#pragma unroll
  for (int m = 0; m < 4; m++)
#pragma unroll
    for (int n = 0; n < 4; n++) acc[m][n] = (f32x4){0.f, 0.f, 0.f, 0.f};

  const int swzl = (l15 & 7) << 4;

  // ---- phase A: Ahi x W_hi  (+ W_lo when full) --------------------------
  for (int kt4 = 0; kt4 < 4; kt4++) {
    const int ka2 = kt4 * 128;           // byte offset of 64-k chunk in 512B row
#pragma unroll
    for (int i = 0; i < 4; i++) {
      int o = tid * 16 + i * 4096;
      int row = o >> 7;
      int sg = ((o >> 4) & 7) ^ (row & 7);
      gload16(Ag_hi + (size_t)(m0 + row) * 512 + ka2 + sg * 16, Al  + wid * 1024 + i * 4096);
      gload16(Bg + (size_t)row * 1536 + ka2 + sg * 16,          Bl1 + wid * 1024 + i * 4096);
      if (full)
        gload16(Bg + (size_t)row * 1536 + 512 + ka2 + sg * 16,  Bl2 + wid * 1024 + i * 4096);
    }
    __syncthreads();

    bf16x8 af[2][4], bfrag[2][4];
#pragma unroll
    for (int kk = 0; kk < 2; kk++)
#pragma unroll
      for (int m = 0; m < 4; m++) {
        af[kk][m]    = *(const bf16x8*)(Al  + (wr * 64 + m * 16 + l15) * 128 + ((kk * 64 + lhi * 16) ^ swzl));
        bfrag[kk][m] = *(const bf16x8*)(Bl1 + (wc * 64 + m * 16 + l15) * 128 + ((kk * 64 + lhi * 16) ^ swzl));
      }
#pragma unroll
    for (int kk = 0; kk < 2; kk++)
#pragma unroll
      for (int m = 0; m < 4; m++)
#pragma unroll
        for (int n = 0; n < 4; n++)
          acc[m][n] = __builtin_amdgcn_mfma_f32_16x16x32_bf16(af[kk][m], bfrag[kk][n], acc[m][n], 0, 0, 0);
    if (full) {
#pragma unroll
      for (int kk = 0; kk < 2; kk++)
#pragma unroll
        for (int m = 0; m < 4; m++)
          bfrag[kk][m] = *(const bf16x8*)(Bl2 + (wc * 64 + m * 16 + l15) * 128 + ((kk * 64 + lhi * 16) ^ swzl));
#pragma unroll
      for (int kk = 0; kk < 2; kk++)
#pragma unroll
        for (int m = 0; m < 4; m++)
#pragma unroll
          for (int n = 0; n < 4; n++)
            acc[m][n] = __builtin_amdgcn_mfma_f32_16x16x32_bf16(af[kk][m], bfrag[kk][n], acc[m][n], 0, 0, 0);
    }
    __syncthreads();
  }

  // ---- phase B: Alo x W_hi (rows 512+k) — S blocks only -----------------
  if (full) {
    for (int kt4 = 0; kt4 < 4; kt4++) {
      const int ka2 = kt4 * 128;
#pragma unroll
      for (int i = 0; i < 4; i++) {
        int o = tid * 16 + i * 4096;
        int row = o >> 7;
        int sg = ((o >> 4) & 7) ^ (row & 7);
        gload16(Ag_lo + (size_t)(m0 + row) * 512 + ka2 + sg * 16, Al  + wid * 1024 + i * 4096);
        gload16(Bg + (size_t)row * 1536 + 1024 + ka2 + sg * 16,   Bl1 + wid * 1024 + i * 4096);
      }
      __syncthreads();

      bf16x8 af[2][4], bfrag[2][4];
#pragma unroll
      for (int kk = 0; kk < 2; kk++)
#pragma unroll
        for (int m = 0; m < 4; m++) {
          af[kk][m]    = *(const bf16x8*)(Al  + (wr * 64 + m * 16 + l15) * 128 + ((kk * 64 + lhi * 16) ^ swzl));
          bfrag[kk][m] = *(const bf16x8*)(Bl1 + (wc * 64 + m * 16 + l15) * 128 + ((kk * 64 + lhi * 16) ^ swzl));
        }
#pragma unroll
      for (int kk = 0; kk < 2; kk++)
#pragma unroll
        for (int m = 0; m < 4; m++)
#pragma unroll
          for (int n = 0; n < 4; n++)
            acc[m][n] = __builtin_amdgcn_mfma_f32_16x16x32_bf16(af[kk][m], bfrag[kk][n], acc[m][n], 0, 0, 0);
      __syncthreads();
    }
  }

  // ---- epilogue ---------------------------------------------------------
  const float* bias = ((nb < 2) ? bq : (nb < 4) ? bk : (nb < 6) ? bv : bs) + layer * 256 + (nb & 1) * 128;
  float bn[4];
#pragma unroll
  for (int n = 0; n < 4; n++) bn[n] = bias[wc * 64 + n * 16 + l15];

  const int col = (nb & 1) * 128 + wc * 64 + l15;
  if (nb < 2) {
#pragma unroll
    for (int m = 0; m < 4; m++) {
#pragma unroll
      for (int r = 0; r < 4; r++) {
        int row = m0 + wr * 64 + m * 16 + lhi * 4 + r;
        if (row < N_NODES) {
          unsigned short* orow = Qb + (size_t)row * 256 + col;
#pragma unroll
          for (int n = 0; n < 4; n++) orow[n * 16] = f2bf(acc[m][n][r] + bn[n]);
        }
      }
    }
  } else if (nb < 6) {
    const int col512 = ((nb >= 4) ? 256 : 0) + col;   // K in [0,256), V in [256,512)
#pragma unroll
    for (int m = 0; m < 4; m++) {
#pragma unroll
      for (int r = 0; r < 4; r++) {
        int row = m0 + wr * 64 + m * 16 + lhi * 4 + r;
        if (row < N_NODES) {
          unsigned short* orow = KVb + (size_t)row * 512 + col512;
#pragma unroll
          for (int n = 0; n < 4; n++) orow[n * 16] = f2bf(acc[m][n][r] + bn[n]);
        }
      }
    }
  } else {
#pragma unroll
    for (int m = 0; m < 4; m++) {
#pragma unroll
      for (int r = 0; r < 4; r++) {
        int row = m0 + wr * 64 + m * 16 + lhi * 4 + r;
        if (row < N_NODES) {
          float* orow = Sf + (size_t)row * 256 + col;
#pragma unroll
          for (int n = 0; n < 4; n++) orow[n * 16] = acc[m][n][r] + bn[n];
        }
      }
    }
  }
}

// ---------------------------------------------------------------- attention
// one wave per dst node; lane l: head l>>4, channels (l&15)*4..+3.
// Q bf16 [N,256]; KV bf16 [N,512]; S fp32 [N,256]. 4-edge batched loads,
// single (m,s,a) online-softmax state with T13 defer-max (RESCALE_THR=8).
// MODE 0: write fp32 [N,256] to hout. MODE 1: write split-bf16 Ahi/Alo.
template <int MODE>
__global__ __launch_bounds__(256) void attn_kernel(
    const unsigned short* __restrict__ Qb,
    const unsigned short* __restrict__ KVb,
    const float* __restrict__ Sf,
    const int* __restrict__ offsets,
    const int* __restrict__ counts,
    const int* __restrict__ ssrc,
    float* __restrict__ hout,
    unsigned short* __restrict__ Ahi,
    unsigned short* __restrict__ Alo) {
  int wv = threadIdx.x >> 6;
  int lane = threadIdx.x & 63;
  int i = blockIdx.x * 4 + wv;
  if (i >= N_NODES) return;

  const int off = (lane >> 4) * 64 + (lane & 15) * 4;

  ushort4 qb = *(const ushort4*)(Qb + (size_t)i * 256 + off);
  float4 q = make_float4(bf2f(qb.x), bf2f(qb.y), bf2f(qb.z), bf2f(qb.w));

  float m = -1e30f, s = 0.f;
  float4 a = make_float4(0.f, 0.f, 0.f, 0.f);

  const int beg = offsets[i];
  const int cnt = counts[i];
  int e = 0;
  for (; e + 4 <= cnt; e += 4) {
    int j[4];
#pragma unroll
    for (int u = 0; u < 4; u++) j[u] = ssrc[beg + e + u];
    ushort4 kk[4], vv[4];
#pragma unroll
    for (int u = 0; u < 4; u++) {
      const unsigned short* base = KVb + (size_t)j[u] * 512;
      kk[u] = *(const ushort4*)(base + off);
      vv[u] = *(const ushort4*)(base + 256 + off);
    }
    float p[4];
#pragma unroll
    for (int u = 0; u < 4; u++)
      p[u] = q.x * bf2f(kk[u].x) + q.y * bf2f(kk[u].y) +
             q.z * bf2f(kk[u].z) + q.w * bf2f(kk[u].w);
#pragma unroll
    for (int u = 0; u < 4; u++) p[u] += __shfl_xor(p[u], 1);
#pragma unroll
    for (int u = 0; u < 4; u++) p[u] += __shfl_xor(p[u], 2);
#pragma unroll
    for (int u = 0; u < 4; u++) p[u] += __shfl_xor(p[u], 4);
#pragma unroll
    for (int u = 0; u < 4; u++) p[u] += __shfl_xor(p[u], 8);
#pragma unroll
    for (int u = 0; u < 4; u++) p[u] *= ATT_SCALE;

    float bm = fmaxf(fmaxf(p[0], p[1]), fmaxf(p[2], p[3]));
    if (!__all(bm <= m + 8.f)) {
      float mn = fmaxf(m, bm);
      float c = __expf(m - mn);
      s *= c; a.x *= c; a.y *= c; a.z *= c; a.w *= c;
      m = mn;
    }
#pragma unroll
    for (int u = 0; u < 4; u++) {
      float w = __expf(p[u] - m);
      s += w;
      a.x += w * bf2f(vv[u].x);
      a.y += w * bf2f(vv[u].y);
      a.z += w * bf2f(vv[u].z);
      a.w += w * bf2f(vv[u].w);
    }
  }
  for (; e < cnt; e++) {
    int j1 = ssrc[beg + e];
    const unsigned short* base = KVb + (size_t)j1 * 512;
    ushort4 k1 = *(const ushort4*)(base + off);
    ushort4 v1 = *(const ushort4*)(base + 256 + off);
    float p1 = q.x * bf2f(k1.x) + q.y * bf2f(k1.y) + q.z * bf2f(k1.z) + q.w * bf2f(k1.w);
    p1 += __shfl_xor(p1, 1);
    p1 += __shfl_xor(p1, 2);
    p1 += __shfl_xor(p1, 4);
    p1 += __shfl_xor(p1, 8);
    p1 *= ATT_SCALE;
    if (!__all(p1 <= m + 8.f)) {
      float mn = fmaxf(m, p1);
      float c = __expf(m - mn);
      s *= c; a.x *= c; a.y *= c; a.z *= c; a.w *= c;
      m = mn;
    }
    float w = __expf(p1 - m);
    s += w;
    a.x += w * bf2f(v1.x);
    a.y += w * bf2f(v1.y);
    a.z += w * bf2f(v1.z);
    a.w += w * bf2f(v1.w);
  }

  float4 sk = *(const float4*)(Sf + (size_t)i * 256 + off);
  float inv = 1.f / (s + 1e-16f);
  float4 o = make_float4(fmaxf(a.x * inv + sk.x, 0.f),
                         fmaxf(a.y * inv + sk.y, 0.f),
                         fmaxf(a.z * inv + sk.z, 0.f),
                         fmaxf(a.w * inv + sk.w, 0.f));
  if (MODE == 0) {
    *(float4*)(hout + (size_t)i * 256 + off) = o;
  } else {
    ushort4 hi, lo;
    hi.x = f2bf(o.x); lo.x = f2bf(o.x - bf2f(hi.x));
    hi.y = f2bf(o.y); lo.y = f2bf(o.y - bf2f(hi.y));
    hi.z = f2bf(o.z); lo.z = f2bf(o.z - bf2f(hi.z));
    hi.w = f2bf(o.w); lo.w = f2bf(o.w - bf2f(hi.w));
    *(ushort4*)(Ahi + (size_t)i * 256 + off) = hi;
    *(ushort4*)(Alo + (size_t)i * 256 + off) = lo;
  }
}

// ---------------------------------------------------------------- fp32 GEMM (fallback, proven)
#define BM 128
#define BN 128
#define BK 16
__global__ __launch_bounds__(256) void gemm_kernel(
    const float* __restrict__ X,
    const float* __restrict__ Wq, const float* __restrict__ Wk,
    const float* __restrict__ Wv, const float* __restrict__ Ws,
    const float* __restrict__ bq, const float* __restrict__ bk,
    const float* __restrict__ bv, const float* __restrict__ bs,
    int layer, float* __restrict__ out) {
  __shared__ __align__(16) float As[BK][BM + 4];
  __shared__ __align__(16) float Bs[BK][BN + 4];
  const int m0 = blockIdx.x * BM;
  const int n0 = blockIdx.y * BN;
  const int wsel = n0 >> 8;
  const float* W;
  const float* bias;
  if (wsel == 0)      { W = Wq; bias = bq; }
  else if (wsel == 1) { W = Wk; bias = bk; }
  else if (wsel == 2) { W = Wv; bias = bv; }
  else                { W = Ws; bias = bs; }
  W += (size_t)layer * 256 * 256;
  bias += (size_t)layer * 256;
  const int nc0 = n0 & 255;
  const int tid = threadIdx.x;
  const int tx = tid & 15;
  const int ty = tid >> 4;
  float acc[8][8];
#pragma unroll
  for (int i = 0; i < 8; i++)
#pragma unroll
    for (int j = 0; j < 8; j++) acc[i][j] = 0.f;
  for (int k0 = 0; k0 < 256; k0 += BK) {
#pragma unroll
    for (int i = 0; i < 8; i++) {
      int idx = tid + i * 256;
      int r = idx >> 4, c = idx & 15;
      int gr = m0 + r;
      As[c][r] = (gr < N_NODES) ? X[(size_t)gr * 256 + k0 + c] : 0.f;
    }
#pragma unroll
    for (int i = 0; i < 8; i++) {
      int idx = tid + i * 256;
      int r = idx >> 7, c = idx & 127;
      Bs[r][c] = W[(size_t)(k0 + r) * 256 + nc0 + c];
    }
    __syncthreads();
#pragma unroll
    for (int k = 0; k < BK; k++) {
      float4 a0 = *(const float4*)&As[k][ty * 8];
      float4 a1 = *(const float4*)&As[k][ty * 8 + 4];
      float4 b0 = *(const float4*)&Bs[k][tx * 8];
      float4 b1 = *(const float4*)&Bs[k][tx * 8 + 4];
      float a[8] = {a0.x, a0.y, a0.z, a0.w, a1.x, a1.y, a1.z, a1.w};
      float b[8] = {b0.x, b0.y, b0.z, b0.w, b1.x, b1.y, b1.z, b1.w};
#pragma unroll
      for (int mi = 0; mi < 8; mi++)
#pragma unroll
        for (int ni = 0; ni < 8; ni++) acc[mi][ni] = fmaf(a[mi], b[ni], acc[mi][ni]);
    }
    __syncthreads();
  }
  float bl[8];
#pragma unroll
  for (int ni = 0; ni < 8; ni++) bl[ni] = bias[nc0 + tx * 8 + ni];
#pragma unroll
  for (int mi = 0; mi < 8; mi++) {
    int row = m0 + ty * 8 + mi;
    if (row < N_NODES) {
      float* orow = out + (size_t)row * 1024 + n0 + tx * 8;
      float4 o0 = make_float4(acc[mi][0] + bl[0], acc[mi][1] + bl[1],
                              acc[mi][2] + bl[2], acc[mi][3] + bl[3]);
      float4 o1 = make_float4(acc[mi][4] + bl[4], acc[mi][5] + bl[5],
                              acc[mi][6] + bl[6], acc[mi][7] + bl[7]);
      *(float4*)orow = o0;
      *(float4*)(orow + 4) = o1;
    }
  }
}

// legacy attention over packed qkvs [N,1024] (fallback path)
__global__ __launch_bounds__(256) void attn_legacy(
    const float* __restrict__ qkvs,
    const int* __restrict__ offsets,
    const int* __restrict__ counts,
    const int* __restrict__ ssrc,
    float* __restrict__ hout) {
  int wv = threadIdx.x >> 6;
  int lane = threadIdx.x & 63;
  int i = blockIdx.x * 4 + wv;
  if (i >= N_NODES) return;
  const int off = (lane >> 4) * 64 + (lane & 15) * 4;
  const float* base_i = qkvs + (size_t)i * 1024;
  float4 q = *(const float4*)(base_i + off);
  float m = -INFINITY, s = 0.f;
  float4 a = make_float4(0.f, 0.f, 0.f, 0.f);
  int beg = offsets[i];
  int cnt = counts[i];
  for (int e = 0; e < cnt; e++) {
    int j = ssrc[beg + e];
    const float* base_j = qkvs + (size_t)j * 1024;
    float4 k = *(const float4*)(base_j + 256 + off);
    float p = q.x * k.x + q.y * k.y + q.z * k.z + q.w * k.w;
    p += __shfl_xor(p, 1);
    p += __shfl_xor(p, 2);
    p += __shfl_xor(p, 4);
    p += __shfl_xor(p, 8);
    p *= ATT_SCALE;
    float4 v = *(const float4*)(base_j + 512 + off);
    float mn = fmaxf(m, p);
    float c = __expf(m - mn);
    float w = __expf(p - mn);
    s = s * c + w;
    a.x = a.x * c + w * v.x;
    a.y = a.y * c + w * v.y;
    a.z = a.z * c + w * v.z;
    a.w = a.w * c + w * v.w;
    m = mn;
  }
  float4 sk = *(const float4*)(base_i + 768 + off);
  float inv = 1.f / (s + 1e-16f);
  float4 o = make_float4(fmaxf(a.x * inv + sk.x, 0.f),
                         fmaxf(a.y * inv + sk.y, 0.f),
                         fmaxf(a.z * inv + sk.z, 0.f),
                         fmaxf(a.w * inv + sk.w, 0.f));
  *(float4*)(hout + (size_t)i * 256 + off) = o;
}

// ---------------------------------------------------------------- launch
extern "C" void kernel_launch(void* const* d_in, const int* in_sizes, int n_in,
                              void* d_out, int out_size, void* d_ws, size_t ws_size,
                              hipStream_t stream) {
  (void)in_sizes; (void)n_in; (void)out_size;
  const float* x   = (const float*)d_in[0];
  const int*   ei  = (const int*)d_in[1];
  const float* Wq  = (const float*)d_in[2];
  const float* bq  = (const float*)d_in[3];
  const float* Wk  = (const float*)d_in[4];
  const float* bk  = (const float*)d_in[5];
  const float* Wv  = (const float*)d_in[6];
  const float* bv  = (const float*)d_in[7];
  const float* Ws_ = (const float*)d_in[8];
  const float* bs  = (const float*)d_in[9];
  float* out = (float*)d_out;

  const int* src = ei;
  const int* dst = ei + N_EDGES;
  char* ws = (char*)d_ws;

  // bf16-path workspace layout (bytes); total 187,768,064
  const size_t NEED = 187768064ull;
  bool big = ws_size >= NEED;

  if (big) {
    unsigned short* Qb   = (unsigned short*)(ws + 0);            //  25,600,000
    unsigned short* KVb  = (unsigned short*)(ws + 25600000);     //  51,200,000
    float*          Sf   = (float*)(ws + 76800000);              //  51,200,000
    unsigned short* Ahi  = (unsigned short*)(ws + 128000000);    //  25,624,576 (50048 rows)
    unsigned short* Alo  = (unsigned short*)(ws + 153624576);    //  25,624,576
    unsigned short* Bexp = (unsigned short*)(ws + 179249152);    //   4,718,592
    int* counts = (int*)(ws + 183967744);
    int* offs   = (int*)(ws + 184167744);
    int* cursor = (int*)(ws + 184367808);
    int* ssrc   = (int*)(ws + 184567808);                        //   3,200,000
    int* btot   = (int*)(ws + 187767808);                        //         256

    zero_int<<<(N_NODES + 255) / 256, 256, 0, stream>>>(counts, N_NODES);
    hist_kernel<<<(N_EDGES + 255) / 256, 256, 0, stream>>>(dst, counts, N_EDGES);
    scan1_kernel<<<(N_NODES + 1023) / 1024, 1024, 0, stream>>>(counts, offs, btot, N_NODES);
    scan2_kernel<<<1, 64, 0, stream>>>(btot, (N_NODES + 1023) / 1024);
    scan3_kernel<<<(N_NODES + 255) / 256, 256, 0, stream>>>(offs, cursor, btot, N_NODES);
    fill_kernel<<<(N_EDGES + 255) / 256, 256, 0, stream>>>(src, dst, cursor, ssrc, N_EDGES);

    convert_w_kernel<<<3072, 256, 0, stream>>>(Wq, Wk, Wv, Ws_, Bexp);
    convert_x_kernel<<<(N_NODES * 64 + 255) / 256, 256, 0, stream>>>(x, Ahi, Alo);

    for (int l = 0; l < 3; l++) {
      bgemm_kernel<<<3128, 256, 0, stream>>>(Ahi, Alo, Bexp, bq, bk, bv, bs, l, Qb, KVb, Sf);
      if (l < 2)
        attn_kernel<1><<<(N_NODES + 3) / 4, 256, 0, stream>>>(Qb, KVb, Sf, offs, counts, ssrc,
                                                              nullptr, Ahi, Alo);
      else
        attn_kernel<0><<<(N_NODES + 3) / 4, 256, 0, stream>>>(Qb, KVb, Sf, offs, counts, ssrc,
                                                              out, nullptr, nullptr);
    }
  } else {
    // fallback: proven fp32 path (round-2 layout)
    float* qkvs   = (float*)(ws + 0);
    float* hbuf   = (float*)(ws + 204800000);
    int*   counts = (int*)(ws + 256000000);
    int*   offs   = (int*)(ws + 256200064);
    int*   cursor = (int*)(ws + 256400128);
    int*   ssrc   = (int*)(ws + 256600192);

    zero_int<<<(N_NODES + 255) / 256, 256, 0, stream>>>(counts, N_NODES);
    hist_kernel<<<(N_EDGES + 255) / 256, 256, 0, stream>>>(dst, counts, N_EDGES);
    scan_kernel<<<1, 1024, 0, stream>>>(counts, offs, cursor, N_NODES);
    fill_kernel<<<(N_EDGES + 255) / 256, 256, 0, stream>>>(src, dst, cursor, ssrc, N_EDGES);

    dim3 ggrid((N_NODES + BM - 1) / BM, 1024 / BN);
    for (int l = 0; l < 3; l++) {
      const float* hin = (l == 0) ? x : hbuf;
      float* hout = (l == 2) ? out : hbuf;
      gemm_kernel<<<ggrid, 256, 0, stream>>>(hin, Wq, Wk, Wv, Ws_, bq, bk, bv, bs, l, qkvs);
      attn_legacy<<<(N_NODES + 3) / 4, 256, 0, stream>>>(qkvs, offs, counts, ssrc, hout);
    }
  }
}